// Round 9
// baseline (630.273 us; speedup 1.0000x reference)
//
#include <hip/hip_runtime.h>
#include <hip/hip_bf16.h>
#include <stdint.h>

// MutualCrossAttention: B=8, C=64, H=W=64 -> T=4096 tokens. Inputs FP32, output FP32.
// dir A: Q=x1, K=V=x2 ; dir B: Q=x2, K=V=x1 ; out = outA + outB, layout [b][c][t].
// R9: occupancy to the 32-wave/CU cap. Block = 512 thr = 8 waves = dir(2) x ks(4),
// all waves share the same 32 q-rows; each wave does 1024 tokens (16 iters).
// Grid = 8b x 128qt = 1024 blocks -> 8192 waves = 8/SIMD. xbuf overlays pbuf
// (dead after the post-loop barrier) so 4 blocks/CU fit in LDS.
// ws: [0,8MB) xt bf16 token-major {x1,x2}; [8MB,16MB) vt bf16 c-major {x1,x2}.

#define TT 4096
#define CC 64
#define NB 8

typedef float f32x4 __attribute__((ext_vector_type(4)));
typedef float f32x4a __attribute__((ext_vector_type(4), may_alias));
typedef short s16x8 __attribute__((ext_vector_type(8)));  // MFMA operand (register value)
typedef unsigned int u32x4a __attribute__((ext_vector_type(4), may_alias));
typedef float f32a __attribute__((may_alias));

static __device__ __forceinline__ unsigned fbits(float x) { return __float_as_uint(x); }
static __device__ __forceinline__ ushort bf16of(float v) {
    return (ushort)((fbits(v) + 0x8000u) >> 16);
}
static __device__ __forceinline__ unsigned pack2(float a, float b) {
    return __builtin_amdgcn_perm(fbits(b) + 0x8000u, fbits(a) + 0x8000u, 0x07060302u);
}
static __device__ __forceinline__ s16x8 load_frag(const void* p) {
    u32x4a t = *(const u32x4a*)p;
    return __builtin_bit_cast(s16x8, t);
}

// Read fp32 x[inp][b][c][t] in 64x64 tiles; emit bf16 token-major xt[inp][b][t][c]
// (via LDS transpose) and bf16 c-major vt[inp][b][c][t].
__global__ void prep_k(const float* __restrict__ x1, const float* __restrict__ x2,
                       ushort* __restrict__ xt, ushort* __restrict__ vt) {
    const int inp = blockIdx.z, b = blockIdx.y, t0 = blockIdx.x * 64;
    const float* src = (inp == 0 ? x1 : x2) + (size_t)b * CC * TT;
    const size_t plane = (size_t)TT * CC;
    ushort* xd = xt + (size_t)(inp * NB + b) * plane;
    ushort* vd = vt + (size_t)(inp * NB + b) * plane;
    __shared__ ushort lds[64][72];
    const int tid = threadIdx.x;
    const int c  = tid >> 2;
    const int tg = tid & 3;
    const float* srow = src + (size_t)c * TT + t0 + tg * 16;
    unsigned hw[8];
#pragma unroll
    for (int i = 0; i < 4; ++i) {
        f32x4a v = *(const f32x4a*)(srow + i * 4);
        hw[2 * i]     = pack2(v[0], v[1]);
        hw[2 * i + 1] = pack2(v[2], v[3]);
#pragma unroll
        for (int k = 0; k < 4; ++k) lds[tg * 16 + i * 4 + k][c] = bf16of(v[k]);
    }
    ushort* vrow = vd + (size_t)c * TT + t0 + tg * 16;
    u32x4a w0 = {hw[0], hw[1], hw[2], hw[3]};
    u32x4a w1 = {hw[4], hw[5], hw[6], hw[7]};
    *(u32x4a*)(vrow) = w0;
    *(u32x4a*)(vrow + 8) = w1;
    __syncthreads();
#pragma unroll
    for (int pass = 0; pass < 2; ++pass) {
        const int t  = (tid >> 3) + pass * 32;
        const int c8 = (tid & 7) * 8;
        u32x4a w = *(const u32x4a*)&lds[t][c8];
        *(u32x4a*)(xd + (size_t)(t0 + t) * CC + c8) = w;
    }
}

// grid = 1024 blocks (qt 0..127 x b 0..7), 512 threads = 8 waves = (ks<<1)|dir.
__global__ __launch_bounds__(512, 8)
void attn_fused_k(const ushort* __restrict__ xt, const ushort* __restrict__ vt,
                  float* __restrict__ out) {
    const int b    = blockIdx.x & 7;
    const int qt   = blockIdx.x >> 3;   // 0..127
    const int tid  = threadIdx.x;
    const int wave = tid >> 6;          // 0..7
    const int lane = tid & 63;
    const int quad = lane >> 4;
    const int l16  = lane & 15;
    const int dir  = wave & 1;
    const int ks   = wave >> 1;         // 0..3
    const int q0   = qt * 32;

    const size_t plane = (size_t)TT * CC;
    const ushort* Qb = xt + (size_t)((dir == 0 ? 0 : NB) + b) * plane;
    const ushort* Kb = xt + (size_t)((dir == 0 ? NB : 0) + b) * plane;
    const ushort* Vb = vt + (size_t)((dir == 0 ? NB : 0) + b) * plane;

    // pbuf: P tile per wave [q16][tok64+8pad] (144B rows, 16B-aligned). 36.9 KB.
    // xbuf (16.4 KB) OVERLAYS pbuf: only used after the post-loop barrier, when
    // all waves are done reading pbuf. lpx is separate (written pre-barrier).
    __shared__ __align__(16) ushort pbuf[8][2][16][72];
    __shared__ float lpx[8][2][4][4];
    f32a* xbuf = (f32a*)&pbuf[0][0][0][0];  // [32 acc slots][64 lanes] f32 = 8 KB

    // Q a-frags: A[m=q=l16][k=c=quad*8+j], loaded once.
    s16x8 qf[2][2];
#pragma unroll
    for (int rb = 0; rb < 2; ++rb)
#pragma unroll
        for (int ch = 0; ch < 2; ++ch)
            qf[rb][ch] = load_frag(Qb + (size_t)(q0 + rb * 16 + l16) * CC + ch * 32 + quad * 8);

    f32x4 accO[2][4];  // O partial (C/D): row=q=quad*4+r (+rb*16), col=c=l16 (+ct*16)
#pragma unroll
    for (int rb = 0; rb < 2; ++rb)
#pragma unroll
        for (int ct = 0; ct < 4; ++ct) accO[rb][ct] = (f32x4){0.f, 0.f, 0.f, 0.f};
    float lp[2][4];
#pragma unroll
    for (int rb = 0; rb < 2; ++rb)
#pragma unroll
        for (int r = 0; r < 4; ++r) lp[rb][r] = 0.f;

    const float C1 = 0.18033688011112042f;  // log2(e)/8 (folds 1/sqrt(64))
    const ushort* kp = Kb + l16 * CC + quad * 8;
    const ushort* vp = Vb + (size_t)l16 * TT + quad * 8;

    const int kt0 = ks * 16;
#pragma unroll 1
    for (int kt = kt0; kt < kt0 + 16; ++kt) {
        const int k0 = kt * 64;
#pragma unroll
        for (int nt = 0; nt < 4; ++nt) {
            s16x8 kf0 = load_frag(kp + (size_t)(k0 + nt * 16) * CC);
            s16x8 kf1 = load_frag(kp + (size_t)(k0 + nt * 16) * CC + 32);
#pragma unroll
            for (int rb = 0; rb < 2; ++rb) {
                f32x4 s = (f32x4){0.f, 0.f, 0.f, 0.f};
                s = __builtin_amdgcn_mfma_f32_16x16x32_bf16(qf[rb][0], kf0, s, 0, 0, 0);
                s = __builtin_amdgcn_mfma_f32_16x16x32_bf16(qf[rb][1], kf1, s, 0, 0, 0);
#pragma unroll
                for (int r = 0; r < 4; ++r) {
                    float p = __builtin_amdgcn_exp2f(fminf(s[r] * C1, 30.f));
                    lp[rb][r] += p;
                    pbuf[wave][rb][quad * 4 + r][nt * 16 + l16] = bf16of(p);
                }
            }
        }
        // O += P·V: A=P (b128 from LDS), B=V[n=c=l16][k=tok=quad*8+j] (bf16 global).
#pragma unroll
        for (int ch2 = 0; ch2 < 2; ++ch2) {
            s16x8 pf[2];
#pragma unroll
            for (int rb = 0; rb < 2; ++rb)
                pf[rb] = load_frag(&pbuf[wave][rb][l16][ch2 * 32 + quad * 8]);
            s16x8 vf[4];
#pragma unroll
            for (int ct = 0; ct < 4; ++ct)
                vf[ct] = load_frag(vp + (size_t)(ct * 16) * TT + k0 + ch2 * 32);
#pragma unroll
            for (int ct = 0; ct < 4; ++ct)
#pragma unroll
                for (int rb = 0; rb < 2; ++rb)
                    accO[rb][ct] = __builtin_amdgcn_mfma_f32_16x16x32_bf16(
                        pf[rb], vf[ct], accO[rb][ct], 0, 0, 0);
        }
    }

    // Wave-local denominator partial: butterfly over l16 bits (cols ≡ l16 mod 16).
#pragma unroll
    for (int rb = 0; rb < 2; ++rb)
#pragma unroll
        for (int r = 0; r < 4; ++r) {
            float l = lp[rb][r];
            l += __shfl_xor(l, 1);
            l += __shfl_xor(l, 2);
            l += __shfl_xor(l, 4);
            l += __shfl_xor(l, 8);
            if (l16 == 0) lpx[wave][rb][quad][r] = l;
        }
    __syncthreads();  // all waves past loop; pbuf dead -> xbuf overlay live

    // Total denominator: sum this dir's 4 ks partials.
    float inv[2][4];
#pragma unroll
    for (int rb = 0; rb < 2; ++rb)
#pragma unroll
        for (int r = 0; r < 4; ++r) {
            float l = lpx[dir][rb][quad][r] + lpx[dir + 2][rb][quad][r] +
                      lpx[dir + 4][rb][quad][r] + lpx[dir + 6][rb][quad][r];
            inv[rb][r] = __builtin_amdgcn_rcpf(l);
        }

    // 8-phase staged accumulation into xbuf; wave 0 finishes in registers + stores.
#pragma unroll 1
    for (int ph = 7; ph >= 1; --ph) {
        if (wave == ph) {
#pragma unroll
            for (int rb = 0; rb < 2; ++rb)
#pragma unroll
                for (int ct = 0; ct < 4; ++ct)
#pragma unroll
                    for (int r = 0; r < 4; ++r) {
                        const int slot = (rb * 16 + ct * 4 + r) * 64 + lane;
                        float v = accO[rb][ct][r] * inv[rb][r];
                        if (ph == 7) xbuf[slot] = v;
                        else xbuf[slot] += v;
                    }
        }
        __syncthreads();
    }
    if (wave == 0) {
        float* ob = out + (size_t)b * plane;
#pragma unroll
        for (int rb = 0; rb < 2; ++rb)
#pragma unroll
            for (int ct = 0; ct < 4; ++ct) {
                f32x4a v;
#pragma unroll
                for (int r = 0; r < 4; ++r)
                    v[r] = accO[rb][ct][r] * inv[rb][r] +
                           xbuf[(rb * 16 + ct * 4 + r) * 64 + lane];
                *(f32x4a*)(ob + (size_t)(ct * 16 + l16) * TT + q0 + rb * 16 + quad * 4) = v;
            }
    }
}

extern "C" void kernel_launch(void* const* d_in, const int* in_sizes, int n_in,
                              void* d_out, int out_size, void* d_ws, size_t ws_size,
                              hipStream_t stream) {
    const float* x1 = (const float*)d_in[0];
    const float* x2 = (const float*)d_in[1];
    ushort* xt = (ushort*)d_ws;                              // 8 MB
    ushort* vt = (ushort*)d_ws + (size_t)2 * NB * TT * CC;   // 8 MB

    hipLaunchKernelGGL(prep_k, dim3(TT / 64, NB, 2), dim3(256), 0, stream, x1, x2, xt, vt);
    hipLaunchKernelGGL(attn_fused_k, dim3(128 * NB), dim3(512), 0, stream,
                       xt, vt, (float*)d_out);
}

// Round 10
// 228.238 us; speedup vs baseline: 2.7615x; 2.7615x over previous
//
#include <hip/hip_runtime.h>
#include <hip/hip_bf16.h>
#include <stdint.h>

// MutualCrossAttention: B=8, C=64, H=W=64 -> T=4096 tokens. Inputs FP32, output FP32.
// dir A: Q=x1, K=V=x2 ; dir B: Q=x2, K=V=x1 ; out = outA + outB, layout [b][c][t].
// R10: K-tiles staged in LDS (register-staged, padded stride -> clean banks) shared
// by all 8 waves; V via global/L1; ks=2 token split keeps 4096 waves = 4/SIMD at
// 128-VGPR budget (R9 showed 8/SIMD forces spills: VGPR=32, FETCH=950MB).
// Block = 512 thr = 8 waves = (ks,pair,dir) over 64 q-rows; grid = 8b x 64qt = 512.
// ws: [0,8MB) xt bf16 token-major {x1,x2}; [8MB,16MB) vt bf16 c-major {x1,x2}.

#define TT 4096
#define CC 64
#define NB 8

typedef float f32x4 __attribute__((ext_vector_type(4)));
typedef float f32x4a __attribute__((ext_vector_type(4), may_alias));
typedef short s16x8 __attribute__((ext_vector_type(8)));  // MFMA operand (register value)
typedef unsigned int u32x4a __attribute__((ext_vector_type(4), may_alias));
typedef float f32a __attribute__((may_alias));

static __device__ __forceinline__ unsigned fbits(float x) { return __float_as_uint(x); }
static __device__ __forceinline__ ushort bf16of(float v) {
    return (ushort)((fbits(v) + 0x8000u) >> 16);
}
static __device__ __forceinline__ unsigned pack2(float a, float b) {
    return __builtin_amdgcn_perm(fbits(b) + 0x8000u, fbits(a) + 0x8000u, 0x07060302u);
}
static __device__ __forceinline__ s16x8 load_frag(const void* p) {
    u32x4a t = *(const u32x4a*)p;
    return __builtin_bit_cast(s16x8, t);
}

// Read fp32 x[inp][b][c][t] in 64x64 tiles; emit bf16 token-major xt[inp][b][t][c]
// (via LDS transpose) and bf16 c-major vt[inp][b][c][t].
__global__ void prep_k(const float* __restrict__ x1, const float* __restrict__ x2,
                       ushort* __restrict__ xt, ushort* __restrict__ vt) {
    const int inp = blockIdx.z, b = blockIdx.y, t0 = blockIdx.x * 64;
    const float* src = (inp == 0 ? x1 : x2) + (size_t)b * CC * TT;
    const size_t plane = (size_t)TT * CC;
    ushort* xd = xt + (size_t)(inp * NB + b) * plane;
    ushort* vd = vt + (size_t)(inp * NB + b) * plane;
    __shared__ ushort lds[64][72];
    const int tid = threadIdx.x;
    const int c  = tid >> 2;
    const int tg = tid & 3;
    const float* srow = src + (size_t)c * TT + t0 + tg * 16;
    unsigned hw[8];
#pragma unroll
    for (int i = 0; i < 4; ++i) {
        f32x4a v = *(const f32x4a*)(srow + i * 4);
        hw[2 * i]     = pack2(v[0], v[1]);
        hw[2 * i + 1] = pack2(v[2], v[3]);
#pragma unroll
        for (int k = 0; k < 4; ++k) lds[tg * 16 + i * 4 + k][c] = bf16of(v[k]);
    }
    ushort* vrow = vd + (size_t)c * TT + t0 + tg * 16;
    u32x4a w0 = {hw[0], hw[1], hw[2], hw[3]};
    u32x4a w1 = {hw[4], hw[5], hw[6], hw[7]};
    *(u32x4a*)(vrow) = w0;
    *(u32x4a*)(vrow + 8) = w1;
    __syncthreads();
#pragma unroll
    for (int pass = 0; pass < 2; ++pass) {
        const int t  = (tid >> 3) + pass * 32;
        const int c8 = (tid & 7) * 8;
        u32x4a w = *(const u32x4a*)&lds[t][c8];
        *(u32x4a*)(xd + (size_t)(t0 + t) * CC + c8) = w;
    }
}

// grid = 512 blocks (qt 0..63 x b 0..7), 512 threads = 8 waves.
// wave: dir = w&1, pair = (w>>1)&1 (32-q half of 64), ks = w>>2 (2048-token half).
__global__ __launch_bounds__(512, 4)
void attn_fused_k(const ushort* __restrict__ xt, const ushort* __restrict__ vt,
                  float* __restrict__ out) {
    const int b    = blockIdx.x & 7;
    const int qt   = blockIdx.x >> 3;   // 0..63
    const int tid  = threadIdx.x;
    const int wave = tid >> 6;          // 0..7
    const int lane = tid & 63;
    const int quad = lane >> 4;
    const int l16  = lane & 15;
    const int dir  = wave & 1;
    const int pair = (wave >> 1) & 1;
    const int ks   = wave >> 2;
    const int q0   = qt * 64 + pair * 32;

    const size_t plane = (size_t)TT * CC;
    const ushort* Qb = xt + (size_t)((dir == 0 ? 0 : NB) + b) * plane;  // token-major
    const ushort* Vb = vt + (size_t)((dir == 0 ? NB : 0) + b) * plane;  // c-major

    // K tile-set: 4 tiles (ks x dir), each [tok64][c64] padded to 72 -> 36.9 KB.
    __shared__ __align__(16) ushort ktile[4][64][72];
    // P per wave: [q16][tok64] stride 72. 36.9 KB. xbuf (16 KB) overlays post-loop.
    __shared__ __align__(16) ushort pbuf[8][2][16][72];
    __shared__ float lpx[8][2][4][4];
    f32a* xbuf = (f32a*)&pbuf[0][0][0][0];  // [pair][32 slots][64 lanes]

    // --- staging role (independent of wave role): tile sub = (sk,sd) ---
    const int sub = tid >> 7;   // 0..3
    const int sk  = sub >> 1;   // staged tile's ks
    const int sd  = sub & 1;    // staged tile's dir
    const int ch0 = tid & 127;  // 16B-chunk base within the 8KB tile (512 chunks)
    const ushort* Ksrc = xt + (size_t)((sd == 0 ? NB : 0) + b) * plane;
    u32x4a st[4];

    auto loadst = [&](int j) {
        const ushort* g = Ksrc + (size_t)(sk * 32 + j) * 64 * CC;  // 8KB contiguous
#pragma unroll
        for (int i = 0; i < 4; ++i)
            st[i] = *(const u32x4a*)(g + (size_t)(ch0 + i * 128) * 8);
    };
    auto wrst = [&]() {
        unsigned* d = (unsigned*)&ktile[sub][0][0];
#pragma unroll
        for (int i = 0; i < 4; ++i) {
            const int c = ch0 + i * 128;               // chunk: row=c>>3, col16=c&7
            *(u32x4a*)&d[(c >> 3) * 36 + (c & 7) * 4] = st[i];
        }
    };

    // Q a-frags: A[m=q=l16][k=c=quad*8+j], loaded once.
    s16x8 qf[2][2];
#pragma unroll
    for (int rb = 0; rb < 2; ++rb)
#pragma unroll
        for (int ch = 0; ch < 2; ++ch)
            qf[rb][ch] = load_frag(Qb + (size_t)(q0 + rb * 16 + l16) * CC + ch * 32 + quad * 8);

    f32x4 accO[2][4];
#pragma unroll
    for (int rb = 0; rb < 2; ++rb)
#pragma unroll
        for (int ct = 0; ct < 4; ++ct) accO[rb][ct] = (f32x4){0.f, 0.f, 0.f, 0.f};
    float lp[2][4];
#pragma unroll
    for (int rb = 0; rb < 2; ++rb)
#pragma unroll
        for (int r = 0; r < 4; ++r) lp[rb][r] = 0.f;

    const float C1 = 0.18033688011112042f;  // log2(e)/8 (folds 1/sqrt(64))
    const ushort* vp = Vb + (size_t)l16 * TT + quad * 8;
    const ushort* kfb = &ktile[ks * 2 + dir][0][0];  // this wave's staged K tile

    loadst(0);
#pragma unroll 1
    for (int j = 0; j < 32; ++j) {
        __syncthreads();              // prev tile-set fully consumed
        wrst();                       // write tile-set j
        if (j < 31) loadst(j + 1);    // prefetch next (latency spans compute)
        __syncthreads();              // tile-set j visible
        const int k0 = (ks * 32 + j) * 64;
        // S = Q·K^T from LDS K tile: B[n=tok=l16][k=c=quad*8+j].
#pragma unroll
        for (int nt = 0; nt < 4; ++nt) {
            const ushort* kr = kfb + (size_t)(nt * 16 + l16) * 72 + quad * 8;
            s16x8 kf0 = load_frag(kr);
            s16x8 kf1 = load_frag(kr + 32);
#pragma unroll
            for (int rb = 0; rb < 2; ++rb) {
                f32x4 s = (f32x4){0.f, 0.f, 0.f, 0.f};
                s = __builtin_amdgcn_mfma_f32_16x16x32_bf16(qf[rb][0], kf0, s, 0, 0, 0);
                s = __builtin_amdgcn_mfma_f32_16x16x32_bf16(qf[rb][1], kf1, s, 0, 0, 0);
#pragma unroll
                for (int r = 0; r < 4; ++r) {
                    float p = __builtin_amdgcn_exp2f(s[r] * C1);
                    lp[rb][r] += p;
                    pbuf[wave][rb][quad * 4 + r][nt * 16 + l16] = bf16of(p);
                }
            }
        }
        // O += P·V: A=P (b128 LDS), B=V[n=c=l16][k=tok=quad*8+j] (bf16 global/L1).
#pragma unroll
        for (int ch2 = 0; ch2 < 2; ++ch2) {
            s16x8 pf[2];
#pragma unroll
            for (int rb = 0; rb < 2; ++rb)
                pf[rb] = load_frag(&pbuf[wave][rb][l16][ch2 * 32 + quad * 8]);
            s16x8 vf[4];
#pragma unroll
            for (int ct = 0; ct < 4; ++ct)
                vf[ct] = load_frag(vp + (size_t)(ct * 16) * TT + k0 + ch2 * 32);
#pragma unroll
            for (int ct = 0; ct < 4; ++ct)
#pragma unroll
                for (int rb = 0; rb < 2; ++rb)
                    accO[rb][ct] = __builtin_amdgcn_mfma_f32_16x16x32_bf16(
                        pf[rb], vf[ct], accO[rb][ct], 0, 0, 0);
        }
    }

    // Wave-local denom (this ks half): butterfly over l16 bits; publish to lpx.
#pragma unroll
    for (int rb = 0; rb < 2; ++rb)
#pragma unroll
        for (int r = 0; r < 4; ++r) {
            float l = lp[rb][r];
            l += __shfl_xor(l, 1);
            l += __shfl_xor(l, 2);
            l += __shfl_xor(l, 4);
            l += __shfl_xor(l, 8);
            lp[rb][r] = l;
            if (l16 == 0) lpx[wave][rb][quad][r] = l;
        }
    __syncthreads();  // all pbuf reads done; lpx visible; xbuf overlay now safe
    float inv[2][4];
#pragma unroll
    for (int rb = 0; rb < 2; ++rb)
#pragma unroll
        for (int r = 0; r < 4; ++r)
            inv[rb][r] = __builtin_amdgcn_rcpf(lp[rb][r] + lpx[wave ^ 4][rb][quad][r]);

    // 4-phase merge over g = (ks,dir) into xbuf[pair]; g==0 stores.
    const int g = ((wave >> 2) << 1) | dir;
#pragma unroll 1
    for (int ph = 3; ph >= 1; --ph) {
        if (g == ph) {
#pragma unroll
            for (int rb = 0; rb < 2; ++rb)
#pragma unroll
                for (int ct = 0; ct < 4; ++ct)
#pragma unroll
                    for (int r = 0; r < 4; ++r) {
                        const int slot = (pair * 32 + rb * 16 + ct * 4 + r) * 64 + lane;
                        float v = accO[rb][ct][r] * inv[rb][r];
                        if (ph == 3) xbuf[slot] = v;
                        else xbuf[slot] += v;
                    }
        }
        __syncthreads();
    }
    if (g == 0) {
        float* ob = out + (size_t)b * plane;
#pragma unroll
        for (int rb = 0; rb < 2; ++rb)
#pragma unroll
            for (int ct = 0; ct < 4; ++ct) {
                f32x4a v;
#pragma unroll
                for (int r = 0; r < 4; ++r)
                    v[r] = accO[rb][ct][r] * inv[rb][r] +
                           xbuf[(pair * 32 + rb * 16 + ct * 4 + r) * 64 + lane];
                *(f32x4a*)(ob + (size_t)(ct * 16 + l16) * TT + q0 + rb * 16 + quad * 4) = v;
            }
    }
}

extern "C" void kernel_launch(void* const* d_in, const int* in_sizes, int n_in,
                              void* d_out, int out_size, void* d_ws, size_t ws_size,
                              hipStream_t stream) {
    const float* x1 = (const float*)d_in[0];
    const float* x2 = (const float*)d_in[1];
    ushort* xt = (ushort*)d_ws;                              // 8 MB
    ushort* vt = (ushort*)d_ws + (size_t)2 * NB * TT * CC;   // 8 MB

    hipLaunchKernelGGL(prep_k, dim3(TT / 64, NB, 2), dim3(256), 0, stream, x1, x2, xt, vt);
    hipLaunchKernelGGL(attn_fused_k, dim3(64 * NB), dim3(512), 0, stream,
                       xt, vt, (float*)d_out);
}